// Round 14
// baseline (101.700 us; speedup 1.0000x reference)
//
#include <hip/hip_runtime.h>

#define S_ROWS 2048
#define RO_ROWS 8192
#define HEADS 8
#define HDIM 32
#define ROWLEN 256           // HEADS * HDIM
#define NB_S (S_ROWS / 16)   // 128 fragment-blocks of s
#define NB_RO (RO_ROWS / 16) // 512 fragment-blocks of ro

typedef __attribute__((ext_vector_type(8))) short bf16x8;
typedef __attribute__((ext_vector_type(4))) float f32x4;
typedef __attribute__((ext_vector_type(4))) short s16x4;

__device__ __forceinline__ short f32_to_bf16_rne(float f) {
    union { float f; unsigned u; } v; v.f = f;
    return (short)((v.u + 0x7fffu + ((v.u >> 16) & 1u)) >> 16);
}

// Normalize every 32-elem head vector; emit bf16 fragments in LANE-LINEAR
// MFMA order: fragment (h, nb) is 1 KiB where byte offset lane*16 holds the
// 8 bf16 that MFMA lane `lane` consumes (row = lane&15, k = (lane>>4)*8..+7).
// Dist then loads operands as frag_base + lane*16B — fully coalesced 1 KiB
// per wave-instruction.
__global__ __launch_bounds__(256) void mhd_normalize(const float* __restrict__ s,
                                                     const float* __restrict__ ro,
                                                     short* __restrict__ sF,
                                                     short* __restrict__ roF) {
    const int v   = blockIdx.x * 256 + threadIdx.x;  // vec4-element id
    const int dg  = v & 7;            // k-elems dg*4 .. dg*4+3
    const int r16 = (v >> 3) & 15;    // row within fragment block
    const int u   = v >> 7;           // (h, nb) chunk id
    const int h   = u & 7;
    const int nb_all = u >> 3;        // 0..639
    const bool isS = nb_all < NB_S;
    const int nb  = isS ? nb_all : nb_all - NB_S;
    const int n   = nb * 16 + r16;    // source row within its tensor

    const float* src = isS ? s : ro;
    f32x4 x = *(const f32x4*)(src + (size_t)n * ROWLEN + h * HDIM + dg * 4);
    float ss = x[0] * x[0] + x[1] * x[1] + x[2] * x[2] + x[3] * x[3];
    ss += __shfl_xor(ss, 1);
    ss += __shfl_xor(ss, 2);
    ss += __shfl_xor(ss, 4);
    const float inv = rsqrtf(ss);
    s16x4 r;
    r[0] = f32_to_bf16_rne(x[0] * inv);
    r[1] = f32_to_bf16_rne(x[1] * inv);
    r[2] = f32_to_bf16_rne(x[2] * inv);
    r[3] = f32_to_bf16_rne(x[3] * inv);

    short* dst = isS ? sF : roF;
    const int NB = isS ? NB_S : NB_RO;
    // lane-linear: lane = (dg>>1)*16 + r16, 16B half = dg&1
    const int lane_in_frag = ((dg >> 1) << 4) + r16;
    const size_t off = ((size_t)(h * NB + nb) << 9) + lane_in_frag * 8 + (dg & 1) * 4;
    *(s16x4*)(dst + off) = r;
}

// Store-microstructure experiment (single variable vs R10):
// identical compute structure (64x64 wave tiles, 8 loads -> 16 MFMA per
// head, register-direct lane-linear fragment loads, 16 waves/CU), but the
// block tile is 128x256 so the epilogue can emit LINEAR 1 KiB stores:
// per 16-row chunk, the 4 waves of a row-band deposit their 64-col slices
// into a shared LDS tile [16][260] (pad 260 -> deposit banks 2-way = free),
// barrier, then each wave stores whole output rows as ONE contiguous 1 KiB
// segment (64 lanes x 16 B). Old epilogues: 4 x 256 B segments at 32 KB
// stride per instr — the hypothesized HBM channel-aliasing bottleneck.
// Grid 512 = 16 row-tiles x 32 col-tiles, XCD-bijective swizzle.
// mfma(b, a): D lane-axis (lane&15) = s-row, reg-axis kg*4+q = ro-col.
__global__ __launch_bounds__(512, 4) void mhd_dist(const short* __restrict__ sF,
                                                   const short* __restrict__ roF,
                                                   float* __restrict__ out) {
    __shared__ float lds[2][16][260];        // 33.3 KiB; 260: deposit 2-way free
    const int lane = threadIdx.x & 63;
    const int wave = threadIdx.x >> 6;       // 0..7
    const int wr = wave >> 2;                // 0..1: 64-row band
    const int wc = wave & 3;                 // 0..3: 64-col quarter
    const int bid = blockIdx.x;
    const int swz = (bid & 7) * 64 + (bid >> 3);   // 512 blocks, 64/XCD
    const int tile_r = swz >> 5;             // 0..15: 128-row tile
    const int tile_c = swz & 31;             // 0..31: 256-col tile
    const int nbA = tile_r * 8 + wr * 4;     // wave's first s fragment-block
    const int nbB = tile_c * 16 + wc * 4;    // wave's first ro fragment-block
    const size_t laneOff = (size_t)lane * 8; // shorts = lane*16B

    f32x4 rmax[4][4];
#pragma unroll
    for (int i = 0; i < 4; ++i)
#pragma unroll
        for (int j = 0; j < 4; ++j)
            rmax[i][j] = (f32x4){-3.0e38f, -3.0e38f, -3.0e38f, -3.0e38f};

#pragma unroll 1
    for (int h = 0; h < HEADS; ++h) {
        const short* aBase = sF  + (((size_t)(h * NB_S  + nbA)) << 9) + laneOff;
        const short* bBase = roF + (((size_t)(h * NB_RO + nbB)) << 9) + laneOff;
        bf16x8 a[4], b[4];
#pragma unroll
        for (int i = 0; i < 4; ++i) {
            a[i] = *(const bf16x8*)(aBase + ((size_t)i << 9));
            b[i] = *(const bf16x8*)(bBase + ((size_t)i << 9));
        }
#pragma unroll
        for (int i = 0; i < 4; ++i)
#pragma unroll
            for (int j = 0; j < 4; ++j) {
                f32x4 acc = {0.f, 0.f, 0.f, 0.f};
                acc = __builtin_amdgcn_mfma_f32_16x16x32_bf16(b[j], a[i], acc, 0, 0, 0);
#pragma unroll
                for (int q2 = 0; q2 < 4; ++q2)
                    rmax[i][j][q2] = fmaxf(rmax[i][j][q2], acc[q2]);
            }
    }

    // Epilogue: per chunk i, both bands deposit 16x256 f32 into lds[band],
    // barrier, then each wave stores 4 whole rows (1 KiB linear each).
    const int l15 = lane & 15;
    const int kg = lane >> 4;
    const int myrow4 = (wave & 3) * 4;       // rows this wave stores
    float* outRowBase = out + (size_t)(tile_r * 128 + wr * 64) * RO_ROWS
                            + tile_c * 256;
#pragma unroll
    for (int i = 0; i < 4; ++i) {
#pragma unroll
        for (int j = 0; j < 4; ++j)
            *(f32x4*)&lds[wr][l15][wc * 64 + kg * 4 + j * 16] = rmax[i][j];
        __syncthreads();
#pragma unroll
        for (int t = 0; t < 4; ++t) {
            const int r16 = myrow4 + t;
            f32x4 vv = *(const f32x4*)&lds[wr][r16][lane * 4];
            *(f32x4*)(outRowBase + (size_t)(i * 16 + r16) * RO_ROWS + lane * 4) = vv;
        }
        if (i < 3) __syncthreads();
    }
}

extern "C" void kernel_launch(void* const* d_in, const int* in_sizes, int n_in,
                              void* d_out, int out_size, void* d_ws, size_t ws_size,
                              hipStream_t stream) {
    const float* batch_s  = (const float*)d_in[0];
    const float* batch_ro = (const float*)d_in[1];
    float* out = (float*)d_out;

    short* sF  = (short*)d_ws;                  // 2048*256 bf16 = 1 MiB
    short* roF = sF + (size_t)S_ROWS * ROWLEN;  // 8192*256 bf16 = 4 MiB

    const int totalV4 = (S_ROWS + RO_ROWS) * ROWLEN / 4;   // 655360 (exact x256)
    mhd_normalize<<<totalV4 / 256, 256, 0, stream>>>(batch_s, batch_ro, sF, roF);

    // 512 blocks: bit0-2 = XCD, rest = (row,col) tile within XCD's strip
    mhd_dist<<<(S_ROWS / 128) * (RO_ROWS / 256), 512, 0, stream>>>(sF, roF, out);
}